// Round 1
// baseline (884.970 us; speedup 1.0000x reference)
//
#include <hip/hip_runtime.h>

// Problem constants (from reference): N=524288 rows, A=256 features, C=19 classes.
#define NROW 524288
#define NA 256
#define NC 19
#define IGN 255
// Per-block partial layout: [sum C*A | sumsq C*A | count C] = 9747 floats
#define SQOFF  (NC * NA)        // 4864
#define CNTOFF (2 * NC * NA)    // 9728
#define NCELL  (2 * NC * NA + NC)  // 9747
#define OUTSTRIDE (2 * NA + 1)  // 513

// ---------------------------------------------------------------------------
// Kernel 1: per-block accumulation of {sum, sumsq, count} per (class, feature).
// Block processes one row at a time; thread t exclusively owns feature column t,
// so the LDS read-modify-write is race-free with NO atomics in the hot loop.
// LDS = 9747*4 = 38988 B -> 4 blocks/CU, 16 waves/CU. HBM-bound by design.
// ---------------------------------------------------------------------------
__global__ __launch_bounds__(256, 4) void k_accum(
    const float* __restrict__ feat, const int* __restrict__ lab,
    float* __restrict__ part, int rpb)
{
    __shared__ float acc[NCELL];
    const int t = threadIdx.x;
    for (int i = t; i < NCELL; i += 256) acc[i] = 0.0f;
    __syncthreads();

    const int r0 = blockIdx.x * rpb;
    const int r1 = min(r0 + rpb, NROW);

    // Counts: disjoint LDS region from sums -> no sync needed vs main loop.
    for (int r = r0 + t; r < r1; r += 256) {
        int c = lab[r];
        if (c != IGN) atomicAdd(&acc[CNTOFF + c], 1.0f);  // ds_add_f32
    }

    // Main streaming loop: 1 coalesced dword load + 2 LDS RMW per element.
    const float* fp = feat + (size_t)r0 * NA + t;
    #pragma unroll 8
    for (int r = r0; r < r1; ++r, fp += NA) {
        int c = lab[r];          // wave-uniform -> scalar load
        float x = *fp;
        if (c != IGN) {          // uniform branch (never taken in bench data)
            int base = c * NA + t;
            acc[base] += x;
            acc[SQOFF + base] += x * x;
        }
    }
    __syncthreads();

    // Coalesced per-block partial write-out (own slice, no atomics).
    float* dst = part + (size_t)blockIdx.x * NCELL;
    for (int i = t; i < NCELL; i += 256) dst[i] = acc[i];
}

// ---------------------------------------------------------------------------
// Kernel 2: reduce [B][NCELL] partials along B into [R][NCELL] slices.
// grid = (ceil(NCELL/256), R). Coalesced: lanes read consecutive cells.
// ---------------------------------------------------------------------------
__global__ void k_reduce(const float* __restrict__ part, float* __restrict__ part2,
                         int nb, int bper)
{
    int col = blockIdx.x * 256 + threadIdx.x;
    if (col >= NCELL) return;
    int b0 = blockIdx.y * bper;
    int b1 = min(b0 + bper, nb);
    float s = 0.0f;
    const float* p = part + (size_t)b0 * NCELL + col;
    for (int b = b0; b < b1; ++b, p += NCELL) s += *p;
    part2[(size_t)blockIdx.y * NCELL + col] = s;
}

// ---------------------------------------------------------------------------
// Kernel 3: finish reduction over R slices, compute mean/var, EMA merge, pack.
// grid = (NC), block = (NA). var via (q - s^2/n)/n in double (cancellation).
// ---------------------------------------------------------------------------
__global__ void k_final(const float* __restrict__ part2, int nr,
                        const float* __restrict__ Mean, const float* __restrict__ CoV,
                        const float* __restrict__ Amt, float* __restrict__ out)
{
    int c = blockIdx.x;   // 0..18
    int a = threadIdx.x;  // 0..255
    float s = 0.0f, q = 0.0f, cnt = 0.0f;
    for (int i = 0; i < nr; ++i) {
        const float* p = part2 + (size_t)i * NCELL;
        s   += p[c * NA + a];
        q   += p[SQOFF + c * NA + a];
        cnt += p[CNTOFF + c];   // same addr per block -> broadcast
    }
    float amt  = Amt[c];
    float cc   = fmaxf(cnt, 1.0f);       // count_c = max(count, 1)
    float mean = s / cc;
    float var  = 0.0f;
    if (cnt > 0.0f) {
        double dv = ((double)q - (double)s * (double)s / (double)cnt) / (double)cnt;
        var = (float)(dv > 0.0 ? dv : 0.0);
    }
    float denom = cnt + amt;
    float w  = (denom != 0.0f) ? (cnt / denom) : 0.0f;  // NaN (0/0) -> 0
    float om = 1.0f - w;
    float mu0 = Mean[c * NA + a];
    float cv0 = CoV[c * NA + a];
    float d   = mu0 - mean;
    float ncv = cv0 * om + var * w + w * om * d * d;
    float nmu = mu0 * om + mean * w;
    out[c * OUTSTRIDE + a]      = ncv;
    out[c * OUTSTRIDE + NA + a] = nmu;
    if (a == 0) out[c * OUTSTRIDE + 2 * NA] = amt + cnt;
}

extern "C" void kernel_launch(void* const* d_in, const int* in_sizes, int n_in,
                              void* d_out, int out_size, void* d_ws, size_t ws_size,
                              hipStream_t stream)
{
    const float* feat = (const float*)d_in[0];
    const int*   lab  = (const int*)d_in[1];
    const float* Mean = (const float*)d_in[2];
    const float* CoV  = (const float*)d_in[3];
    const float* Amt  = (const float*)d_in[4];
    float* out = (float*)d_out;

    // Workspace budget: B partial buffers + R slice buffers of NCELL floats.
    const size_t bufBytes = (size_t)NCELL * sizeof(float);
    size_t cap = ws_size / bufBytes;
    int B = 1024, R = 8;
    if (cap < (size_t)(B + R)) {
        if (cap >= 16) { R = 8; B = (int)cap - R; }
        else if (cap >= 2) { R = 1; B = (int)cap - 1; }
        else { R = 1; B = 1; }  // degenerate; requires ws >= 2 buffers
    }
    if (R > B) R = B;

    float* part  = (float*)d_ws;
    float* part2 = part + (size_t)B * NCELL;
    int rpb  = (NROW + B - 1) / B;
    int bper = (B + R - 1) / R;

    hipLaunchKernelGGL(k_accum, dim3(B), dim3(256), 0, stream,
                       feat, lab, part, rpb);
    hipLaunchKernelGGL(k_reduce, dim3((NCELL + 255) / 256, R), dim3(256), 0, stream,
                       part, part2, B, bper);
    hipLaunchKernelGGL(k_final, dim3(NC), dim3(256), 0, stream,
                       part2, R, Mean, CoV, Amt, out);
}